// Round 1
// baseline (4685.506 us; speedup 1.0000x reference)
//
#include <hip/hip_runtime.h>
#include <math.h>

#define NN 50000
#define NE 800000
#define NG 256
#define H 128
#define NIN 64
#define EIN 16
#define NL 3
#define LEPS 1e-5f

// 64-lane butterfly all-reduce sum
__device__ __forceinline__ float wsum(float v) {
#pragma unroll
  for (int m = 1; m < 64; m <<= 1) v += __shfl_xor(v, m, 64);
  return v;
}

// ---------------- K1: h = LN(x @ Wn + bn) ----------------
// block=256 (4 waves), each wave handles 8 nodes; lane owns cols {lane, lane+64}
__global__ __launch_bounds__(256) void k_node_encode(
    const float* __restrict__ x, const float* __restrict__ W,
    const float* __restrict__ bias,
    const float* __restrict__ lng, const float* __restrict__ lnb,
    float* __restrict__ h) {
  __shared__ float xs[4][8 * NIN];
  const int wave = threadIdx.x >> 6, lane = threadIdx.x & 63;
  const int n0 = (blockIdx.x * 4 + wave) * 8;
  float* xt = xs[wave];
  for (int i = lane; i < 8 * NIN; i += 64) {
    int idx = n0 * NIN + i;
    xt[i] = (idx < NN * NIN) ? x[idx] : 0.f;
  }
  __syncthreads();
  const int c0 = lane, c1 = lane + 64;
  float a0[8], a1[8];
#pragma unroll
  for (int j = 0; j < 8; j++) { a0[j] = 0.f; a1[j] = 0.f; }
  for (int k = 0; k < NIN; k++) {
    float w0 = W[k * H + c0], w1 = W[k * H + c1];
#pragma unroll
    for (int j = 0; j < 8; j++) {
      float xv = xt[j * NIN + k];
      a0[j] = fmaf(xv, w0, a0[j]);
      a1[j] = fmaf(xv, w1, a1[j]);
    }
  }
  const float b0 = bias[c0], b1 = bias[c1];
  const float g0 = lng[c0], g1 = lng[c1], lb0 = lnb[c0], lb1 = lnb[c1];
#pragma unroll
  for (int j = 0; j < 8; j++) {
    float v0 = a0[j] + b0, v1 = a1[j] + b1;
    float mean = wsum(v0 + v1) * (1.f / H);
    float d0 = v0 - mean, d1 = v1 - mean;
    float var = wsum(d0 * d0 + d1 * d1) * (1.f / H);
    float rs = rsqrtf(var + LEPS);
    int n = n0 + j;
    if (n < NN) {
      h[n * H + c0] = d0 * rs * g0 + lb0;
      h[n * H + c1] = d1 * rs * g1 + lb1;
    }
  }
}

// ---------------- K2: hg = h@Wg_top, hm = h@Wm_top ----------------
__global__ __launch_bounds__(256) void k_node_pre(
    const float* __restrict__ h, const float* __restrict__ Wg,
    const float* __restrict__ Wm,
    float* __restrict__ hg, float* __restrict__ hm) {
  __shared__ float hs[4][8 * H];
  const int wave = threadIdx.x >> 6, lane = threadIdx.x & 63;
  const int n0 = (blockIdx.x * 4 + wave) * 8;
  float* ht = hs[wave];
  for (int i = lane; i < 8 * H; i += 64) {
    int idx = n0 * H + i;
    ht[i] = (idx < NN * H) ? h[idx] : 0.f;
  }
  __syncthreads();
  const int c0 = lane, c1 = lane + 64;
  float a0[8], a1[8], b0[8], b1[8];
#pragma unroll
  for (int j = 0; j < 8; j++) { a0[j] = a1[j] = b0[j] = b1[j] = 0.f; }
  for (int k = 0; k < H; k += 4) {
    float wg0[4], wg1[4], wm0[4], wm1[4];
#pragma unroll
    for (int u = 0; u < 4; u++) {
      wg0[u] = Wg[(k + u) * H + c0]; wg1[u] = Wg[(k + u) * H + c1];
      wm0[u] = Wm[(k + u) * H + c0]; wm1[u] = Wm[(k + u) * H + c1];
    }
#pragma unroll
    for (int j = 0; j < 8; j++) {
      float4 v = *(const float4*)&ht[j * H + k];
      a0[j] = fmaf(v.x, wg0[0], a0[j]); a0[j] = fmaf(v.y, wg0[1], a0[j]);
      a0[j] = fmaf(v.z, wg0[2], a0[j]); a0[j] = fmaf(v.w, wg0[3], a0[j]);
      a1[j] = fmaf(v.x, wg1[0], a1[j]); a1[j] = fmaf(v.y, wg1[1], a1[j]);
      a1[j] = fmaf(v.z, wg1[2], a1[j]); a1[j] = fmaf(v.w, wg1[3], a1[j]);
      b0[j] = fmaf(v.x, wm0[0], b0[j]); b0[j] = fmaf(v.y, wm0[1], b0[j]);
      b0[j] = fmaf(v.z, wm0[2], b0[j]); b0[j] = fmaf(v.w, wm0[3], b0[j]);
      b1[j] = fmaf(v.x, wm1[0], b1[j]); b1[j] = fmaf(v.y, wm1[1], b1[j]);
      b1[j] = fmaf(v.z, wm1[2], b1[j]); b1[j] = fmaf(v.w, wm1[3], b1[j]);
    }
  }
#pragma unroll
  for (int j = 0; j < 8; j++) {
    int n = n0 + j;
    if (n < NN) {
      hg[n * H + c0] = a0[j]; hg[n * H + c1] = a1[j];
      hm[n * H + c0] = b0[j]; hm[n * H + c1] = b1[j];
    }
  }
}

// ---------------- K3: fused edge kernel ----------------
// per wave: 8 edges. Phase A: e = LN(ea@We+be). Phase B+C: gate/hidden e-part
// GEMVs (K=128). gather hg/hm[src], activations. Phase D: msg = t@W2. Scatter.
__global__ __launch_bounds__(256) void k_edge(
    const float* __restrict__ ea, const int* __restrict__ eidx,
    const float* __restrict__ hg, const float* __restrict__ hm,
    const float* __restrict__ We, const float* __restrict__ be,
    const float* __restrict__ elng, const float* __restrict__ elnb,
    const float* __restrict__ Wgb, const float* __restrict__ gbias,
    const float* __restrict__ Wmb, const float* __restrict__ mbias1,
    const float* __restrict__ W2, const float* __restrict__ mbias2,
    float* __restrict__ agg) {
  __shared__ float ts[4][8 * H];
  const int wave = threadIdx.x >> 6, lane = threadIdx.x & 63;
  const int e0 = (blockIdx.x * 4 + wave) * 8;   // NE divisible by 32*8? grid is exact: NE/32 blocks * 4 waves * 8
  float* tl = ts[wave];
  const int c0 = lane, c1 = lane + 64;

  // edge-encoder weights register-cached (16x2 per lane)
  float we0[EIN], we1[EIN];
#pragma unroll
  for (int k = 0; k < EIN; k++) { we0[k] = We[k * H + c0]; we1[k] = We[k * H + c1]; }
  const float be0 = be[c0], be1 = be[c1];
  const float eg0 = elng[c0], eg1 = elng[c1], elb0 = elnb[c0], elb1 = elnb[c1];

  // Phase A: encode + LN -> tl holds e rows
  for (int j = 0; j < 8; j++) {
    const float* row = ea + (e0 + j) * EIN;
    float v0 = be0, v1 = be1;
#pragma unroll
    for (int k = 0; k < EIN; k++) {
      float a = row[k];
      v0 = fmaf(a, we0[k], v0);
      v1 = fmaf(a, we1[k], v1);
    }
    float mean = wsum(v0 + v1) * (1.f / H);
    float d0 = v0 - mean, d1 = v1 - mean;
    float var = wsum(d0 * d0 + d1 * d1) * (1.f / H);
    float rs = rsqrtf(var + LEPS);
    tl[j * H + c0] = d0 * rs * eg0 + elb0;
    tl[j * H + c1] = d1 * rs * eg1 + elb1;
  }
  __syncthreads();

  // Phase B+C fused: gate-acc and hidden-acc over e (K=128)
  float ga0[8], ga1[8], ta0[8], ta1[8];
#pragma unroll
  for (int j = 0; j < 8; j++) { ga0[j] = ga1[j] = ta0[j] = ta1[j] = 0.f; }
  for (int k = 0; k < H; k += 4) {
    float wg0[4], wg1[4], wm0[4], wm1[4];
#pragma unroll
    for (int u = 0; u < 4; u++) {
      wg0[u] = Wgb[(k + u) * H + c0]; wg1[u] = Wgb[(k + u) * H + c1];
      wm0[u] = Wmb[(k + u) * H + c0]; wm1[u] = Wmb[(k + u) * H + c1];
    }
#pragma unroll
    for (int j = 0; j < 8; j++) {
      float4 v = *(const float4*)&tl[j * H + k];
      ga0[j] = fmaf(v.x, wg0[0], ga0[j]); ga0[j] = fmaf(v.y, wg0[1], ga0[j]);
      ga0[j] = fmaf(v.z, wg0[2], ga0[j]); ga0[j] = fmaf(v.w, wg0[3], ga0[j]);
      ga1[j] = fmaf(v.x, wg1[0], ga1[j]); ga1[j] = fmaf(v.y, wg1[1], ga1[j]);
      ga1[j] = fmaf(v.z, wg1[2], ga1[j]); ga1[j] = fmaf(v.w, wg1[3], ga1[j]);
      ta0[j] = fmaf(v.x, wm0[0], ta0[j]); ta0[j] = fmaf(v.y, wm0[1], ta0[j]);
      ta0[j] = fmaf(v.z, wm0[2], ta0[j]); ta0[j] = fmaf(v.w, wm0[3], ta0[j]);
      ta1[j] = fmaf(v.x, wm1[0], ta1[j]); ta1[j] = fmaf(v.y, wm1[1], ta1[j]);
      ta1[j] = fmaf(v.z, wm1[2], ta1[j]); ta1[j] = fmaf(v.w, wm1[3], ta1[j]);
    }
  }

  // gather h-parts, activations
  const float gb0 = gbias[c0], gb1 = gbias[c1];
  const float m10 = mbias1[c0], m11 = mbias1[c1];
  float G0[8], G1[8], T0[8], T1[8];
#pragma unroll
  for (int j = 0; j < 8; j++) {
    int s = eidx[e0 + j];
    const float* hgp = hg + s * H;
    const float* hmp = hm + s * H;
    float z0 = ga0[j] + hgp[c0] + gb0;
    float z1 = ga1[j] + hgp[c1] + gb1;
    G0[j] = 1.f / (1.f + expf(-z0));
    G1[j] = 1.f / (1.f + expf(-z1));
    T0[j] = fmaxf(ta0[j] + hmp[c0] + m10, 0.f);
    T1[j] = fmaxf(ta1[j] + hmp[c1] + m11, 0.f);
  }
  __syncthreads();
#pragma unroll
  for (int j = 0; j < 8; j++) { tl[j * H + c0] = T0[j]; tl[j * H + c1] = T1[j]; }
  __syncthreads();

  // Phase D: msg = t @ W2
  float ma0[8], ma1[8];
#pragma unroll
  for (int j = 0; j < 8; j++) { ma0[j] = ma1[j] = 0.f; }
  for (int k = 0; k < H; k += 4) {
    float w0[4], w1[4];
#pragma unroll
    for (int u = 0; u < 4; u++) {
      w0[u] = W2[(k + u) * H + c0]; w1[u] = W2[(k + u) * H + c1];
    }
#pragma unroll
    for (int j = 0; j < 8; j++) {
      float4 v = *(const float4*)&tl[j * H + k];
      ma0[j] = fmaf(v.x, w0[0], ma0[j]); ma0[j] = fmaf(v.y, w0[1], ma0[j]);
      ma0[j] = fmaf(v.z, w0[2], ma0[j]); ma0[j] = fmaf(v.w, w0[3], ma0[j]);
      ma1[j] = fmaf(v.x, w1[0], ma1[j]); ma1[j] = fmaf(v.y, w1[1], ma1[j]);
      ma1[j] = fmaf(v.z, w1[2], ma1[j]); ma1[j] = fmaf(v.w, w1[3], ma1[j]);
    }
  }
  const float m20 = mbias2[c0], m21 = mbias2[c1];
#pragma unroll
  for (int j = 0; j < 8; j++) {
    int d = eidx[NE + e0 + j];
    atomicAdd(&agg[d * H + c0], G0[j] * (ma0[j] + m20));
    atomicAdd(&agg[d * H + c1], G1[j] * (ma1[j] + m21));
  }
}

// ---------------- K4: node update: h = LN(h + MLP([h,agg])) ----------------
__global__ __launch_bounds__(256) void k_node_update(
    const float* __restrict__ agg,
    const float* __restrict__ W1, const float* __restrict__ rb1,
    const float* __restrict__ W2, const float* __restrict__ rb2,
    const float* __restrict__ lng, const float* __restrict__ lnb,
    float* __restrict__ h) {
  __shared__ float hsb[4][8 * H];
  __shared__ float asb[4][8 * H];
  const int wave = threadIdx.x >> 6, lane = threadIdx.x & 63;
  const int n0 = (blockIdx.x * 4 + wave) * 8;
  float* ht = hsb[wave];
  float* at = asb[wave];
  for (int i = lane; i < 8 * H; i += 64) {
    int idx = n0 * H + i;
    bool ok = (idx < NN * H);
    ht[i] = ok ? h[idx] : 0.f;
    at[i] = ok ? agg[idx] : 0.f;
  }
  __syncthreads();
  const int c0 = lane, c1 = lane + 64;
  float a0[8], a1[8];
#pragma unroll
  for (int j = 0; j < 8; j++) { a0[j] = a1[j] = 0.f; }
  // h part: W1 rows [0,128)
  for (int k = 0; k < H; k += 4) {
    float w0[4], w1[4];
#pragma unroll
    for (int u = 0; u < 4; u++) { w0[u] = W1[(k + u) * H + c0]; w1[u] = W1[(k + u) * H + c1]; }
#pragma unroll
    for (int j = 0; j < 8; j++) {
      float4 v = *(const float4*)&ht[j * H + k];
      a0[j] = fmaf(v.x, w0[0], a0[j]); a0[j] = fmaf(v.y, w0[1], a0[j]);
      a0[j] = fmaf(v.z, w0[2], a0[j]); a0[j] = fmaf(v.w, w0[3], a0[j]);
      a1[j] = fmaf(v.x, w1[0], a1[j]); a1[j] = fmaf(v.y, w1[1], a1[j]);
      a1[j] = fmaf(v.z, w1[2], a1[j]); a1[j] = fmaf(v.w, w1[3], a1[j]);
    }
  }
  // agg part: W1 rows [128,256)
  for (int k = 0; k < H; k += 4) {
    float w0[4], w1[4];
#pragma unroll
    for (int u = 0; u < 4; u++) { w0[u] = W1[(128 + k + u) * H + c0]; w1[u] = W1[(128 + k + u) * H + c1]; }
#pragma unroll
    for (int j = 0; j < 8; j++) {
      float4 v = *(const float4*)&at[j * H + k];
      a0[j] = fmaf(v.x, w0[0], a0[j]); a0[j] = fmaf(v.y, w0[1], a0[j]);
      a0[j] = fmaf(v.z, w0[2], a0[j]); a0[j] = fmaf(v.w, w0[3], a0[j]);
      a1[j] = fmaf(v.x, w1[0], a1[j]); a1[j] = fmaf(v.y, w1[1], a1[j]);
      a1[j] = fmaf(v.z, w1[2], a1[j]); a1[j] = fmaf(v.w, w1[3], a1[j]);
    }
  }
  const float rb10 = rb1[c0], rb11 = rb1[c1];
  float T0[8], T1[8];
#pragma unroll
  for (int j = 0; j < 8; j++) {
    T0[j] = fmaxf(a0[j] + rb10, 0.f);
    T1[j] = fmaxf(a1[j] + rb11, 0.f);
  }
  __syncthreads();
#pragma unroll
  for (int j = 0; j < 8; j++) { at[j * H + c0] = T0[j]; at[j * H + c1] = T1[j]; }
  __syncthreads();
  float m0[8], m1[8];
#pragma unroll
  for (int j = 0; j < 8; j++) { m0[j] = m1[j] = 0.f; }
  for (int k = 0; k < H; k += 4) {
    float w0[4], w1[4];
#pragma unroll
    for (int u = 0; u < 4; u++) { w0[u] = W2[(k + u) * H + c0]; w1[u] = W2[(k + u) * H + c1]; }
#pragma unroll
    for (int j = 0; j < 8; j++) {
      float4 v = *(const float4*)&at[j * H + k];
      m0[j] = fmaf(v.x, w0[0], m0[j]); m0[j] = fmaf(v.y, w0[1], m0[j]);
      m0[j] = fmaf(v.z, w0[2], m0[j]); m0[j] = fmaf(v.w, w0[3], m0[j]);
      m1[j] = fmaf(v.x, w1[0], m1[j]); m1[j] = fmaf(v.y, w1[1], m1[j]);
      m1[j] = fmaf(v.z, w1[2], m1[j]); m1[j] = fmaf(v.w, w1[3], m1[j]);
    }
  }
  const float rb20 = rb2[c0], rb21 = rb2[c1];
  const float g0 = lng[c0], g1 = lng[c1], lb0 = lnb[c0], lb1 = lnb[c1];
#pragma unroll
  for (int j = 0; j < 8; j++) {
    float v0 = ht[j * H + c0] + m0[j] + rb20;
    float v1 = ht[j * H + c1] + m1[j] + rb21;
    float mean = wsum(v0 + v1) * (1.f / H);
    float d0 = v0 - mean, d1 = v1 - mean;
    float var = wsum(d0 * d0 + d1 * d1) * (1.f / H);
    float rs = rsqrtf(var + LEPS);
    int n = n0 + j;
    if (n < NN) {
      h[n * H + c0] = d0 * rs * g0 + lb0;
      h[n * H + c1] = d1 * rs * g1 + lb1;
    }
  }
}

// ---------------- K5: pooling (atomic segment sum) ----------------
__global__ __launch_bounds__(256) void k_pool(
    const float* __restrict__ h, const int* __restrict__ batch,
    float* __restrict__ gsum, float* __restrict__ gcnt) {
  int t = blockIdx.x * blockDim.x + threadIdx.x;
  if (t >= NN * H) return;
  int n = t >> 7, c = t & 127;
  int b = batch[n];
  atomicAdd(&gsum[b * H + c], h[t]);
  if (c == 0) atomicAdd(&gcnt[b], 1.f);
}

// ---------------- K6: readout MLP ----------------
__global__ __launch_bounds__(128) void k_readout(
    const float* __restrict__ gsum, const float* __restrict__ gcnt,
    const float* __restrict__ W1, const float* __restrict__ b1,
    const float* __restrict__ W2, const float* __restrict__ b2,
    float* __restrict__ out) {
  __shared__ float gs[H];
  __shared__ float o1[H];
  int b = blockIdx.x, c = threadIdx.x;
  float cnt = fmaxf(gcnt[b], 1.f);
  gs[c] = gsum[b * H + c] / cnt;
  __syncthreads();
  float acc = b1[c];
  for (int k = 0; k < H; k++) acc = fmaf(gs[k], W1[k * H + c], acc);
  o1[c] = fmaxf(acc, 0.f);
  __syncthreads();
  if (c < 2) {
    float acc2 = b2[c];
    for (int k = 0; k < H; k++) acc2 = fmaf(o1[k], W2[k * 2 + c], acc2);
    out[b * 2 + c] = acc2;
  }
}

extern "C" void kernel_launch(void* const* d_in, const int* in_sizes, int n_in,
                              void* d_out, int out_size, void* d_ws, size_t ws_size,
                              hipStream_t stream) {
  (void)in_sizes; (void)n_in; (void)out_size; (void)ws_size;
  const float* x       = (const float*)d_in[0];
  const float* ea      = (const float*)d_in[1];
  const int*   eidx    = (const int*)d_in[2];
  const int*   batch   = (const int*)d_in[3];
  const float* n_enc_w = (const float*)d_in[4];
  const float* n_enc_b = (const float*)d_in[5];
  const float* e_enc_w = (const float*)d_in[6];
  const float* e_enc_b = (const float*)d_in[7];
  const float* n_ln_g  = (const float*)d_in[8];
  const float* n_ln_b  = (const float*)d_in[9];
  const float* e_ln_g  = (const float*)d_in[10];
  const float* e_ln_b  = (const float*)d_in[11];
  const float* msg_w1  = (const float*)d_in[12];
  const float* msg_b1  = (const float*)d_in[13];
  const float* msg_w2  = (const float*)d_in[14];
  const float* msg_b2  = (const float*)d_in[15];
  const float* gate_w  = (const float*)d_in[16];
  const float* gate_b  = (const float*)d_in[17];
  const float* res_w1  = (const float*)d_in[18];
  const float* res_b1  = (const float*)d_in[19];
  const float* res_w2  = (const float*)d_in[20];
  const float* res_b2  = (const float*)d_in[21];
  const float* ln_g    = (const float*)d_in[22];
  const float* ln_b    = (const float*)d_in[23];
  const float* ro_w1   = (const float*)d_in[24];
  const float* ro_b1   = (const float*)d_in[25];
  const float* ro_w2   = (const float*)d_in[26];
  const float* ro_b2   = (const float*)d_in[27];

  float* ws   = (float*)d_ws;
  float* h    = ws;                 // NN*H
  float* hg   = h  + NN * H;        // NN*H
  float* hm   = hg + NN * H;        // NN*H
  float* agg  = hm + NN * H;        // NN*H
  float* gsum = agg + NN * H;       // NG*H
  float* gcnt = gsum + NG * H;      // NG
  // total ~103 MB

  const int node_blocks = (NN + 31) / 32;   // 4 waves x 8 rows per block
  const int edge_blocks = NE / 32;          // exact: 800000 / 32 = 25000

  k_node_encode<<<node_blocks, 256, 0, stream>>>(x, n_enc_w, n_enc_b, n_ln_g, n_ln_b, h);

  for (int l = 0; l < NL; l++) {
    const float* Wg  = gate_w + (size_t)l * 2 * H * H;
    const float* Wm1 = msg_w1 + (size_t)l * 2 * H * H;
    const float* Wm2 = msg_w2 + (size_t)l * H * H;
    const float* W1  = res_w1 + (size_t)l * 2 * H * H;
    const float* W2r = res_w2 + (size_t)l * H * H;

    k_node_pre<<<node_blocks, 256, 0, stream>>>(h, Wg, Wm1, hg, hm);
    hipMemsetAsync(agg, 0, (size_t)NN * H * sizeof(float), stream);
    k_edge<<<edge_blocks, 256, 0, stream>>>(
        ea, eidx, hg, hm, e_enc_w, e_enc_b, e_ln_g, e_ln_b,
        Wg + H * H, gate_b + l * H, Wm1 + H * H, msg_b1 + l * H,
        Wm2, msg_b2 + l * H, agg);
    k_node_update<<<node_blocks, 256, 0, stream>>>(
        agg, W1, res_b1 + l * H, W2r, res_b2 + l * H,
        ln_g + l * H, ln_b + l * H, h);
  }

  hipMemsetAsync(gsum, 0, (size_t)(NG * H + NG) * sizeof(float), stream);
  k_pool<<<(NN * H + 255) / 256, 256, 0, stream>>>(h, batch, gsum, gcnt);
  k_readout<<<NG, 128, 0, stream>>>(gsum, gcnt, ro_w1, ro_b1, ro_w2, ro_b2, (float*)d_out);
}

// Round 2
// 3610.791 us; speedup vs baseline: 1.2976x; 1.2976x over previous
//
#include <hip/hip_runtime.h>
#include <math.h>

#define NN 50000
#define NE 800000
#define NG 256
#define H 128
#define NIN 64
#define EIN 16
#define NL 3
#define LEPS 1e-5f

typedef short bf16x8 __attribute__((ext_vector_type(8)));
typedef float f32x4 __attribute__((ext_vector_type(4)));

// bf16 round-to-nearest-even
__device__ __forceinline__ short bf16rne(float x) {
  unsigned u = __float_as_uint(x);
  unsigned r = u + 0x7fff + ((u >> 16) & 1);
  return (short)(r >> 16);
}

// 64-lane butterfly all-reduce sum
__device__ __forceinline__ float wsum(float v) {
#pragma unroll
  for (int m = 1; m < 64; m <<= 1) v += __shfl_xor(v, m, 64);
  return v;
}

// ---------------- K0: pre-swizzle weights to bf16 MFMA B-fragment layout ----
// Bgh[l]: [K=256][N=256] (cols 0-127 gate_w, 128-255 msg_w1), frag f=nt*8+ks,
//   elem ((f*64+lane)*8+j) <- B[ks*32+(lane>>4)*8+j][nt*16+(lane&15)]
// Bm2[l]: [128][128], f=nt*4+ks
__global__ __launch_bounds__(256) void k_convert_w(
    const float* __restrict__ gate_w, const float* __restrict__ msg_w1,
    const float* __restrict__ msg_w2,
    short* __restrict__ bgh, short* __restrict__ bm2) {
  int tid = blockIdx.x * 256 + threadIdx.x;
  if (tid >= 3 * (65536 + 16384)) return;
  int l = tid / 81920, r = tid % 81920;
  if (r < 65536) {
    int e = r;
    int f = e >> 9, lane = (e >> 3) & 63, j = e & 7;
    int nt = f >> 3, ks = f & 7;
    int k = ks * 32 + (lane >> 4) * 8 + j;
    int n = nt * 16 + (lane & 15);
    float v = (n < 128) ? gate_w[((size_t)l * 256 + k) * 128 + n]
                        : msg_w1[((size_t)l * 256 + k) * 128 + (n - 128)];
    bgh[(size_t)l * 65536 + e] = bf16rne(v);
  } else {
    int e = r - 65536;
    int f = e >> 9, lane = (e >> 3) & 63, j = e & 7;
    int nt = f >> 2, ks = f & 3;
    int k = ks * 32 + (lane >> 4) * 8 + j;
    int n = nt * 16 + (lane & 15);
    bm2[(size_t)l * 16384 + e] = bf16rne(msg_w2[((size_t)l * 128 + k) * 128 + n]);
  }
}

// ---------------- K1: h = LN(x @ Wn + bn) ----------------
__global__ __launch_bounds__(256) void k_node_encode(
    const float* __restrict__ x, const float* __restrict__ W,
    const float* __restrict__ bias,
    const float* __restrict__ lng, const float* __restrict__ lnb,
    float* __restrict__ h) {
  __shared__ float xs[4][8 * NIN];
  const int wave = threadIdx.x >> 6, lane = threadIdx.x & 63;
  const int n0 = (blockIdx.x * 4 + wave) * 8;
  float* xt = xs[wave];
  for (int i = lane; i < 8 * NIN; i += 64) {
    int idx = n0 * NIN + i;
    xt[i] = (idx < NN * NIN) ? x[idx] : 0.f;
  }
  __syncthreads();
  const int c0 = lane, c1 = lane + 64;
  float a0[8], a1[8];
#pragma unroll
  for (int j = 0; j < 8; j++) { a0[j] = 0.f; a1[j] = 0.f; }
  for (int k = 0; k < NIN; k++) {
    float w0 = W[k * H + c0], w1 = W[k * H + c1];
#pragma unroll
    for (int j = 0; j < 8; j++) {
      float xv = xt[j * NIN + k];
      a0[j] = fmaf(xv, w0, a0[j]);
      a1[j] = fmaf(xv, w1, a1[j]);
    }
  }
  const float b0 = bias[c0], b1 = bias[c1];
  const float g0 = lng[c0], g1 = lng[c1], lb0 = lnb[c0], lb1 = lnb[c1];
#pragma unroll
  for (int j = 0; j < 8; j++) {
    float v0 = a0[j] + b0, v1 = a1[j] + b1;
    float mean = wsum(v0 + v1) * (1.f / H);
    float d0 = v0 - mean, d1 = v1 - mean;
    float var = wsum(d0 * d0 + d1 * d1) * (1.f / H);
    float rs = rsqrtf(var + LEPS);
    int n = n0 + j;
    if (n < NN) {
      h[n * H + c0] = d0 * rs * g0 + lb0;
      h[n * H + c1] = d1 * rs * g1 + lb1;
    }
  }
}

// ---------------- K3: MFMA edge kernel ----------------
// block = 256 threads (4 waves), 64 edges. A-tile[64][256] bf16 = [h[src] | e],
// row stride 264 (pad 8 -> 4-bank shift/row). GEMM1 N=256 (gate|hidden),
// epilogue sigmoid/relu, hidden -> T2 overlay (stride 136), GEMM2 N=128,
// msg = gate*(...), atomic scatter to agg[dst].
__global__ __launch_bounds__(256) void k_edge_mfma(
    const float* __restrict__ ea, const int* __restrict__ eidx,
    const float* __restrict__ h,
    const float* __restrict__ We, const float* __restrict__ be,
    const float* __restrict__ elng, const float* __restrict__ elnb,
    const short* __restrict__ Bgh, const short* __restrict__ Bm2,
    const float* __restrict__ gbias, const float* __restrict__ mbias1,
    const float* __restrict__ mbias2,
    float* __restrict__ agg) {
  __shared__ short At[64 * 264];  // 33.8 KB; overlaid by T2[64][136] after GEMM1
  const int tid = threadIdx.x;
  const int wave = tid >> 6, lane = tid & 63;
  const int e0 = blockIdx.x * 64;

  // ---- stage gathered h[src] rows into cols 0-127 (4 threads per row) ----
  {
    int r = tid >> 2;
    int s = eidx[e0 + r];
    const float* hp = h + (size_t)s * H;
    int cbase = (tid & 3) * 4;
    short* drow = At + r * 264;
#pragma unroll
    for (int i = 0; i < 8; i++) {
      int c = cbase + i * 16;
      float4 v = *(const float4*)(hp + c);
      short4 o;
      o.x = bf16rne(v.x); o.y = bf16rne(v.y);
      o.z = bf16rne(v.z); o.w = bf16rne(v.w);
      *(short4*)(drow + c) = o;
    }
  }
  // ---- edge encoder: wave w -> edges [w*16, w*16+16), cols 128-255 ----
  {
    const int c0 = lane, c1 = lane + 64;
    float we0[EIN], we1[EIN];
#pragma unroll
    for (int k = 0; k < EIN; k++) { we0[k] = We[k * H + c0]; we1[k] = We[k * H + c1]; }
    const float be0 = be[c0], be1 = be[c1];
    const float eg0 = elng[c0], eg1 = elng[c1], elb0 = elnb[c0], elb1 = elnb[c1];
    for (int j = 0; j < 16; j++) {
      int row = wave * 16 + j;
      const float* rp = ea + (size_t)(e0 + row) * EIN;
      float v0 = be0, v1 = be1;
#pragma unroll
      for (int k = 0; k < EIN; k++) {
        float a = rp[k];
        v0 = fmaf(a, we0[k], v0);
        v1 = fmaf(a, we1[k], v1);
      }
      float mean = wsum(v0 + v1) * (1.f / H);
      float d0 = v0 - mean, d1 = v1 - mean;
      float var = wsum(d0 * d0 + d1 * d1) * (1.f / H);
      float rs = rsqrtf(var + LEPS);
      At[row * 264 + 128 + c0] = bf16rne(d0 * rs * eg0 + elb0);
      At[row * 264 + 128 + c1] = bf16rne(d1 * rs * eg1 + elb1);
    }
  }
  __syncthreads();

  const int m0 = wave * 16;
  const int mrow = lane & 15, quad = lane >> 4;

  // ---- GEMM1: [16 edges x 256] @ [256 x 256] ----
  bf16x8 af[8];
#pragma unroll
  for (int ks = 0; ks < 8; ks++)
    af[ks] = *(const bf16x8*)&At[(m0 + mrow) * 264 + ks * 32 + quad * 8];
  f32x4 acc[16];
#pragma unroll
  for (int nt = 0; nt < 16; nt++) acc[nt] = (f32x4){0.f, 0.f, 0.f, 0.f};
#pragma unroll
  for (int nt = 0; nt < 16; nt++) {
#pragma unroll
    for (int ks = 0; ks < 8; ks++) {
      bf16x8 bf = *(const bf16x8*)&Bgh[(size_t)((nt * 8 + ks) * 64 + lane) * 8];
      acc[nt] = __builtin_amdgcn_mfma_f32_16x16x32_bf16(af[ks], bf, acc[nt], 0, 0, 0);
    }
  }
  __syncthreads();  // all reads of At done before T2 overlay

  // ---- epilogue 1: gate in regs, hidden -> T2 (bf16, overlay At) ----
  float gate[8][4];
#pragma unroll
  for (int nt = 0; nt < 8; nt++) {
    int col = nt * 16 + mrow;
    float gb = gbias[col];
#pragma unroll
    for (int r = 0; r < 4; r++)
      gate[nt][r] = 1.f / (1.f + expf(-(acc[nt][r] + gb)));
  }
#pragma unroll
  for (int nt = 8; nt < 16; nt++) {
    int col = (nt - 8) * 16 + mrow;
    float mb = mbias1[col];
#pragma unroll
    for (int r = 0; r < 4; r++) {
      int row = m0 + quad * 4 + r;
      At[row * 136 + col] = bf16rne(fmaxf(acc[nt][r] + mb, 0.f));
    }
  }
  __syncthreads();

  // ---- GEMM2: [16 x 128] @ [128 x 128] ----
  bf16x8 a2[4];
#pragma unroll
  for (int ks = 0; ks < 4; ks++)
    a2[ks] = *(const bf16x8*)&At[(m0 + mrow) * 136 + ks * 32 + quad * 8];
  f32x4 acc2[8];
#pragma unroll
  for (int nt = 0; nt < 8; nt++) acc2[nt] = (f32x4){0.f, 0.f, 0.f, 0.f};
#pragma unroll
  for (int nt = 0; nt < 8; nt++) {
#pragma unroll
    for (int ks = 0; ks < 4; ks++) {
      bf16x8 bf = *(const bf16x8*)&Bm2[(size_t)((nt * 4 + ks) * 64 + lane) * 8];
      acc2[nt] = __builtin_amdgcn_mfma_f32_16x16x32_bf16(a2[ks], bf, acc2[nt], 0, 0, 0);
    }
  }

  // ---- epilogue 2: msg = gate*(acc2+b2), atomic scatter ----
  int dstrow[4];
#pragma unroll
  for (int r = 0; r < 4; r++) dstrow[r] = eidx[NE + e0 + m0 + quad * 4 + r];
#pragma unroll
  for (int nt = 0; nt < 8; nt++) {
    int col = nt * 16 + mrow;
    float mb2 = mbias2[col];
#pragma unroll
    for (int r = 0; r < 4; r++) {
      float msg = gate[nt][r] * (acc2[nt][r] + mb2);
      atomicAdd(&agg[(size_t)dstrow[r] * H + col], msg);
    }
  }
}

// ---------------- K4: node update: h = LN(h + MLP([h,agg])) ----------------
__global__ __launch_bounds__(256) void k_node_update(
    const float* __restrict__ agg,
    const float* __restrict__ W1, const float* __restrict__ rb1,
    const float* __restrict__ W2, const float* __restrict__ rb2,
    const float* __restrict__ lng, const float* __restrict__ lnb,
    float* __restrict__ h) {
  __shared__ float hsb[4][8 * H];
  __shared__ float asb[4][8 * H];
  const int wave = threadIdx.x >> 6, lane = threadIdx.x & 63;
  const int n0 = (blockIdx.x * 4 + wave) * 8;
  float* ht = hsb[wave];
  float* at = asb[wave];
  for (int i = lane; i < 8 * H; i += 64) {
    int idx = n0 * H + i;
    bool ok = (idx < NN * H);
    ht[i] = ok ? h[idx] : 0.f;
    at[i] = ok ? agg[idx] : 0.f;
  }
  __syncthreads();
  const int c0 = lane, c1 = lane + 64;
  float a0[8], a1[8];
#pragma unroll
  for (int j = 0; j < 8; j++) { a0[j] = a1[j] = 0.f; }
  for (int k = 0; k < H; k += 4) {
    float w0[4], w1[4];
#pragma unroll
    for (int u = 0; u < 4; u++) { w0[u] = W1[(k + u) * H + c0]; w1[u] = W1[(k + u) * H + c1]; }
#pragma unroll
    for (int j = 0; j < 8; j++) {
      float4 v = *(const float4*)&ht[j * H + k];
      a0[j] = fmaf(v.x, w0[0], a0[j]); a0[j] = fmaf(v.y, w0[1], a0[j]);
      a0[j] = fmaf(v.z, w0[2], a0[j]); a0[j] = fmaf(v.w, w0[3], a0[j]);
      a1[j] = fmaf(v.x, w1[0], a1[j]); a1[j] = fmaf(v.y, w1[1], a1[j]);
      a1[j] = fmaf(v.z, w1[2], a1[j]); a1[j] = fmaf(v.w, w1[3], a1[j]);
    }
  }
  for (int k = 0; k < H; k += 4) {
    float w0[4], w1[4];
#pragma unroll
    for (int u = 0; u < 4; u++) { w0[u] = W1[(128 + k + u) * H + c0]; w1[u] = W1[(128 + k + u) * H + c1]; }
#pragma unroll
    for (int j = 0; j < 8; j++) {
      float4 v = *(const float4*)&at[j * H + k];
      a0[j] = fmaf(v.x, w0[0], a0[j]); a0[j] = fmaf(v.y, w0[1], a0[j]);
      a0[j] = fmaf(v.z, w0[2], a0[j]); a0[j] = fmaf(v.w, w0[3], a0[j]);
      a1[j] = fmaf(v.x, w1[0], a1[j]); a1[j] = fmaf(v.y, w1[1], a1[j]);
      a1[j] = fmaf(v.z, w1[2], a1[j]); a1[j] = fmaf(v.w, w1[3], a1[j]);
    }
  }
  const float rb10 = rb1[c0], rb11 = rb1[c1];
  float T0[8], T1[8];
#pragma unroll
  for (int j = 0; j < 8; j++) {
    T0[j] = fmaxf(a0[j] + rb10, 0.f);
    T1[j] = fmaxf(a1[j] + rb11, 0.f);
  }
  __syncthreads();
#pragma unroll
  for (int j = 0; j < 8; j++) { at[j * H + c0] = T0[j]; at[j * H + c1] = T1[j]; }
  __syncthreads();
  float m0[8], m1[8];
#pragma unroll
  for (int j = 0; j < 8; j++) { m0[j] = m1[j] = 0.f; }
  for (int k = 0; k < H; k += 4) {
    float w0[4], w1[4];
#pragma unroll
    for (int u = 0; u < 4; u++) { w0[u] = W2[(k + u) * H + c0]; w1[u] = W2[(k + u) * H + c1]; }
#pragma unroll
    for (int j = 0; j < 8; j++) {
      float4 v = *(const float4*)&at[j * H + k];
      m0[j] = fmaf(v.x, w0[0], m0[j]); m0[j] = fmaf(v.y, w0[1], m0[j]);
      m0[j] = fmaf(v.z, w0[2], m0[j]); m0[j] = fmaf(v.w, w0[3], m0[j]);
      m1[j] = fmaf(v.x, w1[0], m1[j]); m1[j] = fmaf(v.y, w1[1], m1[j]);
      m1[j] = fmaf(v.z, w1[2], m1[j]); m1[j] = fmaf(v.w, w1[3], m1[j]);
    }
  }
  const float rb20 = rb2[c0], rb21 = rb2[c1];
  const float g0 = lng[c0], g1 = lng[c1], lb0 = lnb[c0], lb1 = lnb[c1];
#pragma unroll
  for (int j = 0; j < 8; j++) {
    float v0 = ht[j * H + c0] + m0[j] + rb20;
    float v1 = ht[j * H + c1] + m1[j] + rb21;
    float mean = wsum(v0 + v1) * (1.f / H);
    float d0 = v0 - mean, d1 = v1 - mean;
    float var = wsum(d0 * d0 + d1 * d1) * (1.f / H);
    float rs = rsqrtf(var + LEPS);
    int n = n0 + j;
    if (n < NN) {
      h[n * H + c0] = d0 * rs * g0 + lb0;
      h[n * H + c1] = d1 * rs * g1 + lb1;
    }
  }
}

// ---------------- K5: pooling ----------------
__global__ __launch_bounds__(256) void k_pool(
    const float* __restrict__ h, const int* __restrict__ batch,
    float* __restrict__ gsum, float* __restrict__ gcnt) {
  int t = blockIdx.x * blockDim.x + threadIdx.x;
  if (t >= NN * H) return;
  int n = t >> 7, c = t & 127;
  int b = batch[n];
  atomicAdd(&gsum[b * H + c], h[t]);
  if (c == 0) atomicAdd(&gcnt[b], 1.f);
}

// ---------------- K6: readout MLP ----------------
__global__ __launch_bounds__(128) void k_readout(
    const float* __restrict__ gsum, const float* __restrict__ gcnt,
    const float* __restrict__ W1, const float* __restrict__ b1,
    const float* __restrict__ W2, const float* __restrict__ b2,
    float* __restrict__ out) {
  __shared__ float gs[H];
  __shared__ float o1[H];
  int b = blockIdx.x, c = threadIdx.x;
  float cnt = fmaxf(gcnt[b], 1.f);
  gs[c] = gsum[b * H + c] / cnt;
  __syncthreads();
  float acc = b1[c];
  for (int k = 0; k < H; k++) acc = fmaf(gs[k], W1[k * H + c], acc);
  o1[c] = fmaxf(acc, 0.f);
  __syncthreads();
  if (c < 2) {
    float acc2 = b2[c];
    for (int k = 0; k < H; k++) acc2 = fmaf(o1[k], W2[k * 2 + c], acc2);
    out[b * 2 + c] = acc2;
  }
}

extern "C" void kernel_launch(void* const* d_in, const int* in_sizes, int n_in,
                              void* d_out, int out_size, void* d_ws, size_t ws_size,
                              hipStream_t stream) {
  (void)in_sizes; (void)n_in; (void)out_size; (void)ws_size;
  const float* x       = (const float*)d_in[0];
  const float* ea      = (const float*)d_in[1];
  const int*   eidx    = (const int*)d_in[2];
  const int*   batch   = (const int*)d_in[3];
  const float* n_enc_w = (const float*)d_in[4];
  const float* n_enc_b = (const float*)d_in[5];
  const float* e_enc_w = (const float*)d_in[6];
  const float* e_enc_b = (const float*)d_in[7];
  const float* n_ln_g  = (const float*)d_in[8];
  const float* n_ln_b  = (const float*)d_in[9];
  const float* e_ln_g  = (const float*)d_in[10];
  const float* e_ln_b  = (const float*)d_in[11];
  const float* msg_w1  = (const float*)d_in[12];
  const float* msg_b1  = (const float*)d_in[13];
  const float* msg_w2  = (const float*)d_in[14];
  const float* msg_b2  = (const float*)d_in[15];
  const float* gate_w  = (const float*)d_in[16];
  const float* gate_b  = (const float*)d_in[17];
  const float* res_w1  = (const float*)d_in[18];
  const float* res_b1  = (const float*)d_in[19];
  const float* res_w2  = (const float*)d_in[20];
  const float* res_b2  = (const float*)d_in[21];
  const float* ln_g    = (const float*)d_in[22];
  const float* ln_b    = (const float*)d_in[23];
  const float* ro_w1   = (const float*)d_in[24];
  const float* ro_b1   = (const float*)d_in[25];
  const float* ro_w2   = (const float*)d_in[26];
  const float* ro_b2   = (const float*)d_in[27];

  float* ws   = (float*)d_ws;
  float* h    = ws;                  // NN*H
  float* agg  = h + (size_t)NN * H;  // NN*H
  float* gsum = agg + (size_t)NN * H;
  float* gcnt = gsum + (size_t)NG * H;
  short* bgh  = (short*)(gcnt + NG);       // 3*65536 bf16
  short* bm2  = bgh + 3 * 65536;           // 3*16384 bf16

  const int node_blocks = (NN + 31) / 32;
  const int edge_blocks = NE / 64;   // 12500, exact

  k_convert_w<<<(3 * 81920 + 255) / 256, 256, 0, stream>>>(gate_w, msg_w1, msg_w2, bgh, bm2);
  k_node_encode<<<node_blocks, 256, 0, stream>>>(x, n_enc_w, n_enc_b, n_ln_g, n_ln_b, h);

  for (int l = 0; l < NL; l++) {
    hipMemsetAsync(agg, 0, (size_t)NN * H * sizeof(float), stream);
    k_edge_mfma<<<edge_blocks, 256, 0, stream>>>(
        ea, eidx, h, e_enc_w, e_enc_b, e_ln_g, e_ln_b,
        bgh + (size_t)l * 65536, bm2 + (size_t)l * 16384,
        gate_b + l * H, msg_b1 + l * H, msg_b2 + l * H, agg);
    k_node_update<<<node_blocks, 256, 0, stream>>>(
        agg, res_w1 + (size_t)l * 2 * H * H, res_b1 + l * H,
        res_w2 + (size_t)l * H * H, res_b2 + l * H,
        ln_g + l * H, ln_b + l * H, h);
  }

  hipMemsetAsync(gsum, 0, (size_t)(NG * H + NG) * sizeof(float), stream);
  k_pool<<<(NN * H + 255) / 256, 256, 0, stream>>>(h, batch, gsum, gcnt);
  k_readout<<<NG, 128, 0, stream>>>(gsum, gcnt, ro_w1, ro_b1, ro_w2, ro_b2, (float*)d_out);
}

// Round 3
// 3030.262 us; speedup vs baseline: 1.5462x; 1.1916x over previous
//
#include <hip/hip_runtime.h>
#include <math.h>

#define NN 50000
#define NE 800000
#define NG 256
#define H 128
#define NIN 64
#define EIN 16
#define NL 3
#define LEPS 1e-5f

typedef short bf16x8 __attribute__((ext_vector_type(8)));
typedef float f32x4 __attribute__((ext_vector_type(4)));

__device__ __forceinline__ short bf16rne(float x) {
  unsigned u = __float_as_uint(x);
  unsigned r = u + 0x7fff + ((u >> 16) & 1);
  return (short)(r >> 16);
}

__device__ __forceinline__ float wsum(float v) {
#pragma unroll
  for (int m = 1; m < 64; m <<= 1) v += __shfl_xor(v, m, 64);
  return v;
}

// ---------------- sort-by-dst pipeline (once per launch) ----------------
__global__ __launch_bounds__(256) void k_count(const int* __restrict__ eidx,
                                               unsigned* __restrict__ cnt) {
  int t = blockIdx.x * 256 + threadIdx.x;
  if (t < NE) atomicAdd(&cnt[eidx[NE + t]], 1u);
}

// single-block exclusive scan of cnt[NN] -> rowptr[NN]
__global__ __launch_bounds__(1024) void k_scan(const unsigned* __restrict__ cnt,
                                               unsigned* __restrict__ rowptr) {
  __shared__ unsigned part[16];
  __shared__ unsigned carry_s;
  const int tid = threadIdx.x, lane = tid & 63, wid = tid >> 6;
  if (tid == 0) carry_s = 0;
  __syncthreads();
  for (int base = 0; base < NN; base += 1024) {
    int i = base + tid;
    unsigned v = (i < NN) ? cnt[i] : 0u;
    unsigned incl = v;
#pragma unroll
    for (int off = 1; off < 64; off <<= 1) {
      unsigned t = __shfl_up(incl, off, 64);
      if (lane >= off) incl += t;
    }
    if (lane == 63) part[wid] = incl;
    __syncthreads();
    if (tid == 0) {
      unsigned s = 0;
#pragma unroll
      for (int w = 0; w < 16; w++) { unsigned t = part[w]; part[w] = s; s += t; }
    }
    __syncthreads();
    unsigned carry = carry_s;
    if (i < NN) rowptr[i] = carry + part[wid] + incl - v;
    __syncthreads();
    if (tid == 1023) carry_s = carry + part[15] + incl;
    __syncthreads();
  }
}

__global__ __launch_bounds__(256) void k_scatter(
    const int* __restrict__ eidx, const float* __restrict__ ea,
    const unsigned* __restrict__ rowptr, unsigned* __restrict__ cursor,
    int* __restrict__ src_s, int* __restrict__ dst_s,
    float* __restrict__ ea_s) {
  int t = blockIdx.x * 256 + threadIdx.x;
  if (t >= NE) return;
  int s = eidx[t], d = eidx[NE + t];
  unsigned pos = rowptr[d] + atomicAdd(&cursor[d], 1u);
  src_s[pos] = s;
  dst_s[pos] = d;
  const float4* er = (const float4*)(ea + (size_t)t * EIN);
  float4 a = er[0], b = er[1], c = er[2], e = er[3];
  float4* ow = (float4*)(ea_s + (size_t)pos * EIN);
  ow[0] = a; ow[1] = b; ow[2] = c; ow[3] = e;
}

// ---------------- K0: pre-swizzle weights to bf16 B-fragment layout ----------
__global__ __launch_bounds__(256) void k_convert_w(
    const float* __restrict__ gate_w, const float* __restrict__ msg_w1,
    const float* __restrict__ msg_w2,
    short* __restrict__ bgh, short* __restrict__ bm2) {
  int tid = blockIdx.x * 256 + threadIdx.x;
  if (tid >= 3 * (65536 + 16384)) return;
  int l = tid / 81920, r = tid % 81920;
  if (r < 65536) {
    int e = r;
    int f = e >> 9, lane = (e >> 3) & 63, j = e & 7;
    int nt = f >> 3, ks = f & 7;
    int k = ks * 32 + (lane >> 4) * 8 + j;
    int n = nt * 16 + (lane & 15);
    float v = (n < 128) ? gate_w[((size_t)l * 256 + k) * 128 + n]
                        : msg_w1[((size_t)l * 256 + k) * 128 + (n - 128)];
    bgh[(size_t)l * 65536 + e] = bf16rne(v);
  } else {
    int e = r - 65536;
    int f = e >> 9, lane = (e >> 3) & 63, j = e & 7;
    int nt = f >> 2, ks = f & 3;
    int k = ks * 32 + (lane >> 4) * 8 + j;
    int n = nt * 16 + (lane & 15);
    bm2[(size_t)l * 16384 + e] = bf16rne(msg_w2[((size_t)l * 128 + k) * 128 + n]);
  }
}

// ---------------- K1: h = LN(x @ Wn + bn) ----------------
__global__ __launch_bounds__(256) void k_node_encode(
    const float* __restrict__ x, const float* __restrict__ W,
    const float* __restrict__ bias,
    const float* __restrict__ lng, const float* __restrict__ lnb,
    float* __restrict__ h) {
  __shared__ float xs[4][8 * NIN];
  const int wave = threadIdx.x >> 6, lane = threadIdx.x & 63;
  const int n0 = (blockIdx.x * 4 + wave) * 8;
  float* xt = xs[wave];
  for (int i = lane; i < 8 * NIN; i += 64) {
    int idx = n0 * NIN + i;
    xt[i] = (idx < NN * NIN) ? x[idx] : 0.f;
  }
  __syncthreads();
  const int c0 = lane, c1 = lane + 64;
  float a0[8], a1[8];
#pragma unroll
  for (int j = 0; j < 8; j++) { a0[j] = 0.f; a1[j] = 0.f; }
  for (int k = 0; k < NIN; k++) {
    float w0 = W[k * H + c0], w1 = W[k * H + c1];
#pragma unroll
    for (int j = 0; j < 8; j++) {
      float xv = xt[j * NIN + k];
      a0[j] = fmaf(xv, w0, a0[j]);
      a1[j] = fmaf(xv, w1, a1[j]);
    }
  }
  const float b0 = bias[c0], b1 = bias[c1];
  const float g0 = lng[c0], g1 = lng[c1], lb0 = lnb[c0], lb1 = lnb[c1];
#pragma unroll
  for (int j = 0; j < 8; j++) {
    float v0 = a0[j] + b0, v1 = a1[j] + b1;
    float mean = wsum(v0 + v1) * (1.f / H);
    float d0 = v0 - mean, d1 = v1 - mean;
    float var = wsum(d0 * d0 + d1 * d1) * (1.f / H);
    float rs = rsqrtf(var + LEPS);
    int n = n0 + j;
    if (n < NN) {
      h[n * H + c0] = d0 * rs * g0 + lb0;
      h[n * H + c1] = d1 * rs * g1 + lb1;
    }
  }
}

// ---------------- K3: MFMA edge kernel, dst-sorted edges ----------------
__global__ __launch_bounds__(256) void k_edge_mfma(
    const float* __restrict__ ea_s, const int* __restrict__ src_s,
    const int* __restrict__ dst_s, const float* __restrict__ h,
    const float* __restrict__ We, const float* __restrict__ be,
    const float* __restrict__ elng, const float* __restrict__ elnb,
    const short* __restrict__ Bgh, const short* __restrict__ Bm2,
    const float* __restrict__ gbias, const float* __restrict__ mbias1,
    const float* __restrict__ mbias2,
    float* __restrict__ agg) {
  __shared__ short At[64 * 264];     // A-tile, 33.8 KB; rows wave-partitioned
  __shared__ float eas[64 * EIN];    // staged ea rows, 4 KB
  const int tid = threadIdx.x;
  const int wave = tid >> 6, lane = tid & 63;
  const int e0 = blockIdx.x * 64;

  // ---- stage gathered h[src] rows into cols 0-127 + ea rows (coalesced) ----
  {
    int r = tid >> 2;
    int s = src_s[e0 + r];
    const float* hp = h + (size_t)s * H;
    int cbase = (tid & 3) * 4;
    short* drow = At + r * 264;
#pragma unroll
    for (int i = 0; i < 8; i++) {
      int c = cbase + i * 16;
      float4 v = *(const float4*)(hp + c);
      short4 o;
      o.x = bf16rne(v.x); o.y = bf16rne(v.y);
      o.z = bf16rne(v.z); o.w = bf16rne(v.w);
      *(short4*)(drow + c) = o;
    }
    float4 ev = *(const float4*)(ea_s + (size_t)(e0 + r) * EIN + cbase);
    *(float4*)(eas + r * EIN + cbase) = ev;
  }
  __syncthreads();

  // ---- edge encoder: wave w -> rows [w*16, w*16+16), A cols 128-255 ----
  {
    const int c0 = lane, c1 = lane + 64;
    float we0[EIN], we1[EIN];
#pragma unroll
    for (int k = 0; k < EIN; k++) { we0[k] = We[k * H + c0]; we1[k] = We[k * H + c1]; }
    const float be0 = be[c0], be1 = be[c1];
    const float eg0 = elng[c0], eg1 = elng[c1], elb0 = elnb[c0], elb1 = elnb[c1];
    for (int j = 0; j < 16; j++) {
      int row = wave * 16 + j;
      const float* er = eas + row * EIN;   // wave-uniform -> LDS broadcast
      float4 q0 = *(const float4*)(er);
      float4 q1 = *(const float4*)(er + 4);
      float4 q2 = *(const float4*)(er + 8);
      float4 q3 = *(const float4*)(er + 12);
      float av[EIN] = {q0.x,q0.y,q0.z,q0.w, q1.x,q1.y,q1.z,q1.w,
                       q2.x,q2.y,q2.z,q2.w, q3.x,q3.y,q3.z,q3.w};
      float v0 = be0, v1 = be1;
#pragma unroll
      for (int k = 0; k < EIN; k++) {
        v0 = fmaf(av[k], we0[k], v0);
        v1 = fmaf(av[k], we1[k], v1);
      }
      float mean = wsum(v0 + v1) * (1.f / H);
      float d0 = v0 - mean, d1 = v1 - mean;
      float var = wsum(d0 * d0 + d1 * d1) * (1.f / H);
      float rs = rsqrtf(var + LEPS);
      At[row * 264 + 128 + c0] = bf16rne(d0 * rs * eg0 + elb0);
      At[row * 264 + 128 + c1] = bf16rne(d1 * rs * eg1 + elb1);
    }
  }
  __syncthreads();

  const int m0 = wave * 16;
  const int mrow = lane & 15, quad = lane >> 4;

  // ---- GEMM1: [16 edges x 256] @ [256 x 256] (gate | hidden) ----
  bf16x8 af[8];
#pragma unroll
  for (int ks = 0; ks < 8; ks++)
    af[ks] = *(const bf16x8*)&At[(m0 + mrow) * 264 + ks * 32 + quad * 8];
  f32x4 acc[16];
#pragma unroll
  for (int nt = 0; nt < 16; nt++) acc[nt] = (f32x4){0.f, 0.f, 0.f, 0.f};
#pragma unroll
  for (int nt = 0; nt < 16; nt++) {
#pragma unroll
    for (int ks = 0; ks < 8; ks++) {
      bf16x8 bf = *(const bf16x8*)&Bgh[(size_t)((nt * 8 + ks) * 64 + lane) * 8];
      acc[nt] = __builtin_amdgcn_mfma_f32_16x16x32_bf16(af[ks], bf, acc[nt], 0, 0, 0);
    }
  }
  __syncthreads();

  // ---- epilogue 1: gate in regs, hidden -> wave-private T2 (stride 136) ----
  short* T2 = At + wave * (16 * 264);
  float gate[8][4];
#pragma unroll
  for (int nt = 0; nt < 8; nt++) {
    int col = nt * 16 + mrow;
    float gb = gbias[col];
#pragma unroll
    for (int r = 0; r < 4; r++)
      gate[nt][r] = 1.f / (1.f + expf(-(acc[nt][r] + gb)));
  }
#pragma unroll
  for (int nt = 8; nt < 16; nt++) {
    int col = (nt - 8) * 16 + mrow;
    float mb = mbias1[col];
#pragma unroll
    for (int r = 0; r < 4; r++)
      T2[(quad * 4 + r) * 136 + col] = bf16rne(fmaxf(acc[nt][r] + mb, 0.f));
  }
  __syncthreads();

  // ---- GEMM2: [16 x 128] @ [128 x 128] ----
  bf16x8 a2[4];
#pragma unroll
  for (int ks = 0; ks < 4; ks++)
    a2[ks] = *(const bf16x8*)&T2[mrow * 136 + ks * 32 + quad * 8];
  f32x4 acc2[8];
#pragma unroll
  for (int nt = 0; nt < 8; nt++) acc2[nt] = (f32x4){0.f, 0.f, 0.f, 0.f};
#pragma unroll
  for (int nt = 0; nt < 8; nt++) {
#pragma unroll
    for (int ks = 0; ks < 4; ks++) {
      bf16x8 bf = *(const bf16x8*)&Bm2[(size_t)((nt * 4 + ks) * 64 + lane) * 8];
      acc2[nt] = __builtin_amdgcn_mfma_f32_16x16x32_bf16(a2[ks], bf, acc2[nt], 0, 0, 0);
    }
  }

  // ---- epilogue 2: msg = gate*(acc2+b2); run-reduce over sorted dst ----
  const int gr = e0 + m0 + quad * 4;
  const int d0 = dst_s[gr], d1 = dst_s[gr + 1], d2 = dst_s[gr + 2], d3 = dst_s[gr + 3];
#pragma unroll
  for (int nt = 0; nt < 8; nt++) {
    int col = nt * 16 + mrow;
    float mb2 = mbias2[col];
    float v0 = gate[nt][0] * (acc2[nt][0] + mb2);
    float v1 = gate[nt][1] * (acc2[nt][1] + mb2);
    float v2 = gate[nt][2] * (acc2[nt][2] + mb2);
    float v3 = gate[nt][3] * (acc2[nt][3] + mb2);
    float run = v0;
    int cur = d0;
    if (d1 == cur) run += v1;
    else { atomicAdd(&agg[(size_t)cur * H + col], run); cur = d1; run = v1; }
    if (d2 == cur) run += v2;
    else { atomicAdd(&agg[(size_t)cur * H + col], run); cur = d2; run = v2; }
    if (d3 == cur) run += v3;
    else { atomicAdd(&agg[(size_t)cur * H + col], run); cur = d3; run = v3; }
    atomicAdd(&agg[(size_t)cur * H + col], run);
  }
}

// ---------------- K4: node update: h = LN(h + MLP([h,agg])) ----------------
__global__ __launch_bounds__(256) void k_node_update(
    const float* __restrict__ agg,
    const float* __restrict__ W1, const float* __restrict__ rb1,
    const float* __restrict__ W2, const float* __restrict__ rb2,
    const float* __restrict__ lng, const float* __restrict__ lnb,
    float* __restrict__ h) {
  __shared__ float hsb[4][8 * H];
  __shared__ float asb[4][8 * H];
  const int wave = threadIdx.x >> 6, lane = threadIdx.x & 63;
  const int n0 = (blockIdx.x * 4 + wave) * 8;
  float* ht = hsb[wave];
  float* at = asb[wave];
  for (int i = lane; i < 8 * H; i += 64) {
    int idx = n0 * H + i;
    bool ok = (idx < NN * H);
    ht[i] = ok ? h[idx] : 0.f;
    at[i] = ok ? agg[idx] : 0.f;
  }
  __syncthreads();
  const int c0 = lane, c1 = lane + 64;
  float a0[8], a1[8];
#pragma unroll
  for (int j = 0; j < 8; j++) { a0[j] = a1[j] = 0.f; }
  for (int k = 0; k < H; k += 4) {
    float w0[4], w1[4];
#pragma unroll
    for (int u = 0; u < 4; u++) { w0[u] = W1[(k + u) * H + c0]; w1[u] = W1[(k + u) * H + c1]; }
#pragma unroll
    for (int j = 0; j < 8; j++) {
      float4 v = *(const float4*)&ht[j * H + k];
      a0[j] = fmaf(v.x, w0[0], a0[j]); a0[j] = fmaf(v.y, w0[1], a0[j]);
      a0[j] = fmaf(v.z, w0[2], a0[j]); a0[j] = fmaf(v.w, w0[3], a0[j]);
      a1[j] = fmaf(v.x, w1[0], a1[j]); a1[j] = fmaf(v.y, w1[1], a1[j]);
      a1[j] = fmaf(v.z, w1[2], a1[j]); a1[j] = fmaf(v.w, w1[3], a1[j]);
    }
  }
  for (int k = 0; k < H; k += 4) {
    float w0[4], w1[4];
#pragma unroll
    for (int u = 0; u < 4; u++) { w0[u] = W1[(128 + k + u) * H + c0]; w1[u] = W1[(128 + k + u) * H + c1]; }
#pragma unroll
    for (int j = 0; j < 8; j++) {
      float4 v = *(const float4*)&at[j * H + k];
      a0[j] = fmaf(v.x, w0[0], a0[j]); a0[j] = fmaf(v.y, w0[1], a0[j]);
      a0[j] = fmaf(v.z, w0[2], a0[j]); a0[j] = fmaf(v.w, w0[3], a0[j]);
      a1[j] = fmaf(v.x, w1[0], a1[j]); a1[j] = fmaf(v.y, w1[1], a1[j]);
      a1[j] = fmaf(v.z, w1[2], a1[j]); a1[j] = fmaf(v.w, w1[3], a1[j]);
    }
  }
  const float rb10 = rb1[c0], rb11 = rb1[c1];
  float T0[8], T1[8];
#pragma unroll
  for (int j = 0; j < 8; j++) {
    T0[j] = fmaxf(a0[j] + rb10, 0.f);
    T1[j] = fmaxf(a1[j] + rb11, 0.f);
  }
  __syncthreads();
#pragma unroll
  for (int j = 0; j < 8; j++) { at[j * H + c0] = T0[j]; at[j * H + c1] = T1[j]; }
  __syncthreads();
  float m0[8], m1[8];
#pragma unroll
  for (int j = 0; j < 8; j++) { m0[j] = m1[j] = 0.f; }
  for (int k = 0; k < H; k += 4) {
    float w0[4], w1[4];
#pragma unroll
    for (int u = 0; u < 4; u++) { w0[u] = W2[(k + u) * H + c0]; w1[u] = W2[(k + u) * H + c1]; }
#pragma unroll
    for (int j = 0; j < 8; j++) {
      float4 v = *(const float4*)&at[j * H + k];
      m0[j] = fmaf(v.x, w0[0], m0[j]); m0[j] = fmaf(v.y, w0[1], m0[j]);
      m0[j] = fmaf(v.z, w0[2], m0[j]); m0[j] = fmaf(v.w, w0[3], m0[j]);
      m1[j] = fmaf(v.x, w1[0], m1[j]); m1[j] = fmaf(v.y, w1[1], m1[j]);
      m1[j] = fmaf(v.z, w1[2], m1[j]); m1[j] = fmaf(v.w, w1[3], m1[j]);
    }
  }
  const float rb20 = rb2[c0], rb21 = rb2[c1];
  const float g0 = lng[c0], g1 = lng[c1], lb0 = lnb[c0], lb1 = lnb[c1];
#pragma unroll
  for (int j = 0; j < 8; j++) {
    float v0 = ht[j * H + c0] + m0[j] + rb20;
    float v1 = ht[j * H + c1] + m1[j] + rb21;
    float mean = wsum(v0 + v1) * (1.f / H);
    float d0 = v0 - mean, d1 = v1 - mean;
    float var = wsum(d0 * d0 + d1 * d1) * (1.f / H);
    float rs = rsqrtf(var + LEPS);
    int n = n0 + j;
    if (n < NN) {
      h[n * H + c0] = d0 * rs * g0 + lb0;
      h[n * H + c1] = d1 * rs * g1 + lb1;
    }
  }
}

// ---------------- K5: pooling ----------------
__global__ __launch_bounds__(256) void k_pool(
    const float* __restrict__ h, const int* __restrict__ batch,
    float* __restrict__ gsum, float* __restrict__ gcnt) {
  int t = blockIdx.x * blockDim.x + threadIdx.x;
  if (t >= NN * H) return;
  int n = t >> 7, c = t & 127;
  int b = batch[n];
  atomicAdd(&gsum[b * H + c], h[t]);
  if (c == 0) atomicAdd(&gcnt[b], 1.f);
}

// ---------------- K6: readout MLP ----------------
__global__ __launch_bounds__(128) void k_readout(
    const float* __restrict__ gsum, const float* __restrict__ gcnt,
    const float* __restrict__ W1, const float* __restrict__ b1,
    const float* __restrict__ W2, const float* __restrict__ b2,
    float* __restrict__ out) {
  __shared__ float gs[H];
  __shared__ float o1[H];
  int b = blockIdx.x, c = threadIdx.x;
  float cnt = fmaxf(gcnt[b], 1.f);
  gs[c] = gsum[b * H + c] / cnt;
  __syncthreads();
  float acc = b1[c];
  for (int k = 0; k < H; k++) acc = fmaf(gs[k], W1[k * H + c], acc);
  o1[c] = fmaxf(acc, 0.f);
  __syncthreads();
  if (c < 2) {
    float acc2 = b2[c];
    for (int k = 0; k < H; k++) acc2 = fmaf(o1[k], W2[k * 2 + c], acc2);
    out[b * 2 + c] = acc2;
  }
}

extern "C" void kernel_launch(void* const* d_in, const int* in_sizes, int n_in,
                              void* d_out, int out_size, void* d_ws, size_t ws_size,
                              hipStream_t stream) {
  (void)in_sizes; (void)n_in; (void)out_size; (void)ws_size;
  const float* x       = (const float*)d_in[0];
  const float* ea      = (const float*)d_in[1];
  const int*   eidx    = (const int*)d_in[2];
  const int*   batch   = (const int*)d_in[3];
  const float* n_enc_w = (const float*)d_in[4];
  const float* n_enc_b = (const float*)d_in[5];
  const float* e_enc_w = (const float*)d_in[6];
  const float* e_enc_b = (const float*)d_in[7];
  const float* n_ln_g  = (const float*)d_in[8];
  const float* n_ln_b  = (const float*)d_in[9];
  const float* e_ln_g  = (const float*)d_in[10];
  const float* e_ln_b  = (const float*)d_in[11];
  const float* msg_w1  = (const float*)d_in[12];
  const float* msg_b1  = (const float*)d_in[13];
  const float* msg_w2  = (const float*)d_in[14];
  const float* msg_b2  = (const float*)d_in[15];
  const float* gate_w  = (const float*)d_in[16];
  const float* gate_b  = (const float*)d_in[17];
  const float* res_w1  = (const float*)d_in[18];
  const float* res_b1  = (const float*)d_in[19];
  const float* res_w2  = (const float*)d_in[20];
  const float* res_b2  = (const float*)d_in[21];
  const float* ln_g    = (const float*)d_in[22];
  const float* ln_b    = (const float*)d_in[23];
  const float* ro_w1   = (const float*)d_in[24];
  const float* ro_b1   = (const float*)d_in[25];
  const float* ro_w2   = (const float*)d_in[26];
  const float* ro_b2   = (const float*)d_in[27];

  char* p = (char*)d_ws;
  float* h     = (float*)p;  p += (size_t)NN * H * 4;          // 25.6 MB
  float* agg   = (float*)p;  p += (size_t)NN * H * 4;          // 25.6 MB
  float* ea_s  = (float*)p;  p += (size_t)NE * EIN * 4;        // 51.2 MB
  float* gsum  = (float*)p;  p += (size_t)NG * H * 4;
  float* gcnt  = (float*)p;  p += 1024;
  short* bgh   = (short*)p;  p += 3 * 65536 * 2;
  short* bm2   = (short*)p;  p += 3 * 16384 * 2;
  unsigned* rowptr = (unsigned*)p; p += ((size_t)NN * 4 + 15) / 16 * 16;
  unsigned* cursor = (unsigned*)p; p += ((size_t)NN * 4 + 15) / 16 * 16;
  int* src_s   = (int*)p;    p += (size_t)NE * 4;
  int* dst_s   = (int*)p;    p += (size_t)NE * 4;
  // total ~110 MB

  const int node_blocks = (NN + 31) / 32;
  const int edge_blocks = NE / 64;
  const int e256 = (NE + 255) / 256;

  // sort edges by dst (counting sort), once per launch
  hipMemsetAsync(cursor, 0, (size_t)NN * 4, stream);
  k_count<<<e256, 256, 0, stream>>>(eidx, cursor);
  k_scan<<<1, 1024, 0, stream>>>(cursor, rowptr);
  hipMemsetAsync(cursor, 0, (size_t)NN * 4, stream);
  k_scatter<<<e256, 256, 0, stream>>>(eidx, ea, rowptr, cursor, src_s, dst_s, ea_s);

  k_convert_w<<<(3 * 81920 + 255) / 256, 256, 0, stream>>>(gate_w, msg_w1, msg_w2, bgh, bm2);
  k_node_encode<<<node_blocks, 256, 0, stream>>>(x, n_enc_w, n_enc_b, n_ln_g, n_ln_b, h);

  for (int l = 0; l < NL; l++) {
    hipMemsetAsync(agg, 0, (size_t)NN * H * 4, stream);
    k_edge_mfma<<<edge_blocks, 256, 0, stream>>>(
        ea_s, src_s, dst_s, h, e_enc_w, e_enc_b, e_ln_g, e_ln_b,
        bgh + (size_t)l * 65536, bm2 + (size_t)l * 16384,
        gate_b + l * H, msg_b1 + l * H, msg_b2 + l * H, agg);
    k_node_update<<<node_blocks, 256, 0, stream>>>(
        agg, res_w1 + (size_t)l * 2 * H * H, res_b1 + l * H,
        res_w2 + (size_t)l * H * H, res_b2 + l * H,
        ln_g + l * H, ln_b + l * H, h);
  }

  hipMemsetAsync(gsum, 0, ((size_t)NG * H + NG) * 4, stream);
  k_pool<<<(NN * H + 255) / 256, 256, 0, stream>>>(h, batch, gsum, gcnt);
  k_readout<<<NG, 128, 0, stream>>>(gsum, gcnt, ro_w1, ro_b1, ro_w2, ro_b2, (float*)d_out);
}

// Round 4
// 2362.620 us; speedup vs baseline: 1.9832x; 1.2826x over previous
//
#include <hip/hip_runtime.h>
#include <math.h>

#define NN 50000
#define NE 800000
#define NG 256
#define H 128
#define NIN 64
#define EIN 16
#define NL 3
#define LEPS 1e-5f

typedef short bf16x8 __attribute__((ext_vector_type(8)));
typedef float f32x4 __attribute__((ext_vector_type(4)));

__device__ __forceinline__ short bf16rne(float x) {
  unsigned u = __float_as_uint(x);
  unsigned r = u + 0x7fff + ((u >> 16) & 1);
  return (short)(r >> 16);
}

__device__ __forceinline__ float wsum(float v) {
#pragma unroll
  for (int m = 1; m < 64; m <<= 1) v += __shfl_xor(v, m, 64);
  return v;
}

// ---------------- sort-by-dst pipeline (once per launch) ----------------
__global__ __launch_bounds__(256) void k_count(const int* __restrict__ eidx,
                                               unsigned* __restrict__ cnt) {
  int t = blockIdx.x * 256 + threadIdx.x;
  if (t < NE) atomicAdd(&cnt[eidx[NE + t]], 1u);
}

__global__ __launch_bounds__(1024) void k_scan(const unsigned* __restrict__ cnt,
                                               unsigned* __restrict__ rowptr) {
  __shared__ unsigned part[16];
  __shared__ unsigned carry_s;
  const int tid = threadIdx.x, lane = tid & 63, wid = tid >> 6;
  if (tid == 0) carry_s = 0;
  __syncthreads();
  for (int base = 0; base < NN; base += 1024) {
    int i = base + tid;
    unsigned v = (i < NN) ? cnt[i] : 0u;
    unsigned incl = v;
#pragma unroll
    for (int off = 1; off < 64; off <<= 1) {
      unsigned t = __shfl_up(incl, off, 64);
      if (lane >= off) incl += t;
    }
    if (lane == 63) part[wid] = incl;
    __syncthreads();
    if (tid == 0) {
      unsigned s = 0;
#pragma unroll
      for (int w = 0; w < 16; w++) { unsigned t = part[w]; part[w] = s; s += t; }
    }
    __syncthreads();
    unsigned carry = carry_s;
    if (i < NN) rowptr[i] = carry + part[wid] + incl - v;
    __syncthreads();
    if (tid == 1023) carry_s = carry + part[15] + incl;
    __syncthreads();
  }
}

// scatter: permute edges into dst-sorted order; ea converted to bf16 rows
__global__ __launch_bounds__(256) void k_scatter(
    const int* __restrict__ eidx, const float* __restrict__ ea,
    const unsigned* __restrict__ rowptr, unsigned* __restrict__ cursor,
    int* __restrict__ src_s, int* __restrict__ dst_s,
    short* __restrict__ ea_bf) {
  int t = blockIdx.x * 256 + threadIdx.x;
  if (t >= NE) return;
  int s = eidx[t], d = eidx[NE + t];
  unsigned pos = rowptr[d] + atomicAdd(&cursor[d], 1u);
  src_s[pos] = s;
  dst_s[pos] = d;
  const float4* er = (const float4*)(ea + (size_t)t * EIN);
  float4 q0 = er[0], q1 = er[1], q2 = er[2], q3 = er[3];
  short tmp[16];
  tmp[0]=bf16rne(q0.x); tmp[1]=bf16rne(q0.y); tmp[2]=bf16rne(q0.z); tmp[3]=bf16rne(q0.w);
  tmp[4]=bf16rne(q1.x); tmp[5]=bf16rne(q1.y); tmp[6]=bf16rne(q1.z); tmp[7]=bf16rne(q1.w);
  tmp[8]=bf16rne(q2.x); tmp[9]=bf16rne(q2.y); tmp[10]=bf16rne(q2.z); tmp[11]=bf16rne(q2.w);
  tmp[12]=bf16rne(q3.x); tmp[13]=bf16rne(q3.y); tmp[14]=bf16rne(q3.z); tmp[15]=bf16rne(q3.w);
  short* dstp = ea_bf + (size_t)pos * EIN;
  *(bf16x8*)dstp = *(bf16x8*)tmp;
  *(bf16x8*)(dstp + 8) = *(bf16x8*)(tmp + 8);
}

// ---------------- K0: pre-swizzle weights to bf16 B-fragment layout ----------
// Bgh[l]: [256][256] (cols 0-127 gate, 128-255 hidden); Bm2[l]: [128][128];
// Benc: [32][128] K-padded encoder weights (rows 16-31 zero).
__global__ __launch_bounds__(256) void k_convert_w(
    const float* __restrict__ gate_w, const float* __restrict__ msg_w1,
    const float* __restrict__ msg_w2, const float* __restrict__ e_enc_w,
    short* __restrict__ bgh, short* __restrict__ bm2, short* __restrict__ benc) {
  int tid = blockIdx.x * 256 + threadIdx.x;
  const int TOT = 3 * 81920 + 4096;
  if (tid >= TOT) return;
  if (tid >= 3 * 81920) {
    int e = tid - 3 * 81920;
    int nt = e >> 9, lane = (e >> 3) & 63, j = e & 7;
    int k = (lane >> 4) * 8 + j;
    int n = nt * 16 + (lane & 15);
    benc[e] = (k < EIN) ? bf16rne(e_enc_w[k * H + n]) : (short)0;
    return;
  }
  int l = tid / 81920, r = tid % 81920;
  if (r < 65536) {
    int e = r;
    int f = e >> 9, lane = (e >> 3) & 63, j = e & 7;
    int nt = f >> 3, ks = f & 7;
    int k = ks * 32 + (lane >> 4) * 8 + j;
    int n = nt * 16 + (lane & 15);
    float v = (n < 128) ? gate_w[((size_t)l * 256 + k) * 128 + n]
                        : msg_w1[((size_t)l * 256 + k) * 128 + (n - 128)];
    bgh[(size_t)l * 65536 + e] = bf16rne(v);
  } else {
    int e = r - 65536;
    int f = e >> 9, lane = (e >> 3) & 63, j = e & 7;
    int nt = f >> 2, ks = f & 3;
    int k = ks * 32 + (lane >> 4) * 8 + j;
    int n = nt * 16 + (lane & 15);
    bm2[(size_t)l * 16384 + e] = bf16rne(msg_w2[((size_t)l * 128 + k) * 128 + n]);
  }
}

// ---------------- K1: h = LN(x @ Wn + bn), also emit bf16 copy ----------------
__global__ __launch_bounds__(256) void k_node_encode(
    const float* __restrict__ x, const float* __restrict__ W,
    const float* __restrict__ bias,
    const float* __restrict__ lng, const float* __restrict__ lnb,
    float* __restrict__ h, short* __restrict__ h_bf) {
  __shared__ float xs[4][8 * NIN];
  const int wave = threadIdx.x >> 6, lane = threadIdx.x & 63;
  const int n0 = (blockIdx.x * 4 + wave) * 8;
  float* xt = xs[wave];
  for (int i = lane; i < 8 * NIN; i += 64) {
    int idx = n0 * NIN + i;
    xt[i] = (idx < NN * NIN) ? x[idx] : 0.f;
  }
  __syncthreads();
  const int c0 = lane, c1 = lane + 64;
  float a0[8], a1[8];
#pragma unroll
  for (int j = 0; j < 8; j++) { a0[j] = 0.f; a1[j] = 0.f; }
  for (int k = 0; k < NIN; k++) {
    float w0 = W[k * H + c0], w1 = W[k * H + c1];
#pragma unroll
    for (int j = 0; j < 8; j++) {
      float xv = xt[j * NIN + k];
      a0[j] = fmaf(xv, w0, a0[j]);
      a1[j] = fmaf(xv, w1, a1[j]);
    }
  }
  const float b0 = bias[c0], b1 = bias[c1];
  const float g0 = lng[c0], g1 = lng[c1], lb0 = lnb[c0], lb1 = lnb[c1];
#pragma unroll
  for (int j = 0; j < 8; j++) {
    float v0 = a0[j] + b0, v1 = a1[j] + b1;
    float mean = wsum(v0 + v1) * (1.f / H);
    float d0 = v0 - mean, d1 = v1 - mean;
    float var = wsum(d0 * d0 + d1 * d1) * (1.f / H);
    float rs = rsqrtf(var + LEPS);
    int n = n0 + j;
    if (n < NN) {
      float o0 = d0 * rs * g0 + lb0, o1 = d1 * rs * g1 + lb1;
      h[n * H + c0] = o0;
      h[n * H + c1] = o1;
      h_bf[n * H + c0] = bf16rne(o0);
      h_bf[n * H + c1] = bf16rne(o1);
    }
  }
}

// ---------------- K3: MFMA edge kernel, barrier-free, dst-sorted ----------------
// 4 waves x 16 edges. Wave-private LDS region [16 x 136] bf16 holds e then T2.
__global__ __launch_bounds__(256, 4) void k_edge_mfma(
    const short* __restrict__ ea_bf, const int* __restrict__ src_s,
    const int* __restrict__ dst_s, const short* __restrict__ h_bf,
    const short* __restrict__ Benc, const float* __restrict__ be,
    const float* __restrict__ elng, const float* __restrict__ elnb,
    const short* __restrict__ Bgh, const short* __restrict__ Bm2,
    const float* __restrict__ gbias, const float* __restrict__ mbias1,
    const float* __restrict__ mbias2,
    float* __restrict__ agg) {
  __shared__ short regn[4][16 * 136];
  const int tid = threadIdx.x;
  const int wave = tid >> 6, lane = tid & 63;
  const int e0 = blockIdx.x * 64 + wave * 16;
  short* R = regn[wave];
  const int mrow = lane & 15, quad = lane >> 4;

  // ---- encoder: e = LN(ea @ We + be) via MFMA (K padded 16->32) ----
  bf16x8 ae = (bf16x8){0, 0, 0, 0, 0, 0, 0, 0};
  if (quad < 2)
    ae = *(const bf16x8*)(ea_bf + (size_t)(e0 + mrow) * EIN + quad * 8);
  float vals[8][4];
  float gE[8], bE[8];
#pragma unroll
  for (int nt = 0; nt < 8; nt++) {
    bf16x8 bf = *(const bf16x8*)(Benc + (nt * 64 + lane) * 8);
    f32x4 c = __builtin_amdgcn_mfma_f32_16x16x32_bf16(
        ae, bf, (f32x4){0.f, 0.f, 0.f, 0.f}, 0, 0, 0);
    int col = nt * 16 + mrow;
    float bev = be[col];
    gE[nt] = elng[col]; bE[nt] = elnb[col];
#pragma unroll
    for (int r = 0; r < 4; r++) vals[nt][r] = c[r] + bev;
  }
#pragma unroll
  for (int r = 0; r < 4; r++) {
    float s1 = 0.f, s2 = 0.f;
#pragma unroll
    for (int nt = 0; nt < 8; nt++) {
      s1 += vals[nt][r];
      s2 = fmaf(vals[nt][r], vals[nt][r], s2);
    }
#pragma unroll
    for (int m = 1; m < 16; m <<= 1) {
      s1 += __shfl_xor(s1, m, 64);
      s2 += __shfl_xor(s2, m, 64);
    }
    float mean = s1 * (1.f / 128.f);
    float var = s2 * (1.f / 128.f) - mean * mean;
    float rs = rsqrtf(var + LEPS);
    int row = quad * 4 + r;
#pragma unroll
    for (int nt = 0; nt < 8; nt++)
      R[row * 136 + nt * 16 + mrow] =
          bf16rne((vals[nt][r] - mean) * rs * gE[nt] + bE[nt]);
  }

  // ---- GEMM1 A-frags: h part direct from global (bf16), e part from LDS ----
  const int srow = src_s[e0 + mrow];
  bf16x8 af[8];
#pragma unroll
  for (int ks = 0; ks < 4; ks++)
    af[ks] = *(const bf16x8*)(h_bf + (size_t)srow * H + ks * 32 + quad * 8);
#pragma unroll
  for (int ks = 0; ks < 4; ks++)
    af[4 + ks] = *(const bf16x8*)&R[mrow * 136 + ks * 32 + quad * 8];

  // ---- hidden pass (Bgh nt 8..15): relu -> T2 (overlays e region) ----
  f32x4 acc[8];
#pragma unroll
  for (int t = 0; t < 8; t++) acc[t] = (f32x4){0.f, 0.f, 0.f, 0.f};
#pragma unroll
  for (int t = 0; t < 8; t++) {
#pragma unroll
    for (int ks = 0; ks < 8; ks++) {
      bf16x8 bf = *(const bf16x8*)(Bgh + (size_t)(((t + 8) * 8 + ks) * 64 + lane) * 8);
      acc[t] = __builtin_amdgcn_mfma_f32_16x16x32_bf16(af[ks], bf, acc[t], 0, 0, 0);
    }
  }
#pragma unroll
  for (int t = 0; t < 8; t++) {
    int col = t * 16 + mrow;
    float mb = mbias1[col];
#pragma unroll
    for (int r = 0; r < 4; r++)
      R[(quad * 4 + r) * 136 + col] = bf16rne(fmaxf(acc[t][r] + mb, 0.f));
  }

  // ---- gate pass (Bgh nt 0..7): sigmoid -> regs ----
#pragma unroll
  for (int t = 0; t < 8; t++) acc[t] = (f32x4){0.f, 0.f, 0.f, 0.f};
#pragma unroll
  for (int t = 0; t < 8; t++) {
#pragma unroll
    for (int ks = 0; ks < 8; ks++) {
      bf16x8 bf = *(const bf16x8*)(Bgh + (size_t)((t * 8 + ks) * 64 + lane) * 8);
      acc[t] = __builtin_amdgcn_mfma_f32_16x16x32_bf16(af[ks], bf, acc[t], 0, 0, 0);
    }
  }
  float gate[8][4];
#pragma unroll
  for (int t = 0; t < 8; t++) {
    int col = t * 16 + mrow;
    float gb = gbias[col];
#pragma unroll
    for (int r = 0; r < 4; r++)
      gate[t][r] = 1.f / (1.f + expf(-(acc[t][r] + gb)));
  }

  // ---- GEMM2: msg_hidden @ W2 ----
  bf16x8 a2[4];
#pragma unroll
  for (int ks = 0; ks < 4; ks++)
    a2[ks] = *(const bf16x8*)&R[mrow * 136 + ks * 32 + quad * 8];
  f32x4 acc2[8];
#pragma unroll
  for (int t = 0; t < 8; t++) acc2[t] = (f32x4){0.f, 0.f, 0.f, 0.f};
#pragma unroll
  for (int t = 0; t < 8; t++) {
#pragma unroll
    for (int ks = 0; ks < 4; ks++) {
      bf16x8 bf = *(const bf16x8*)(Bm2 + (size_t)((t * 4 + ks) * 64 + lane) * 8);
      acc2[t] = __builtin_amdgcn_mfma_f32_16x16x32_bf16(a2[ks], bf, acc2[t], 0, 0, 0);
    }
  }

  // ---- epilogue: msg = gate*(acc2+b2); run-reduce over sorted dst ----
  const int gr = e0 + quad * 4;
  const int d0 = dst_s[gr], d1 = dst_s[gr + 1], d2 = dst_s[gr + 2], d3 = dst_s[gr + 3];
#pragma unroll
  for (int t = 0; t < 8; t++) {
    int col = t * 16 + mrow;
    float mb2 = mbias2[col];
    float v0 = gate[t][0] * (acc2[t][0] + mb2);
    float v1 = gate[t][1] * (acc2[t][1] + mb2);
    float v2 = gate[t][2] * (acc2[t][2] + mb2);
    float v3 = gate[t][3] * (acc2[t][3] + mb2);
    float run = v0;
    int cur = d0;
    if (d1 == cur) run += v1;
    else { atomicAdd(&agg[(size_t)cur * H + col], run); cur = d1; run = v1; }
    if (d2 == cur) run += v2;
    else { atomicAdd(&agg[(size_t)cur * H + col], run); cur = d2; run = v2; }
    if (d3 == cur) run += v3;
    else { atomicAdd(&agg[(size_t)cur * H + col], run); cur = d3; run = v3; }
    atomicAdd(&agg[(size_t)cur * H + col], run);
  }
}

// ---------------- K4: node update: h = LN(h + MLP([h,agg])), emit bf16 ---------
__global__ __launch_bounds__(256) void k_node_update(
    const float* __restrict__ agg,
    const float* __restrict__ W1, const float* __restrict__ rb1,
    const float* __restrict__ W2, const float* __restrict__ rb2,
    const float* __restrict__ lng, const float* __restrict__ lnb,
    float* __restrict__ h, short* __restrict__ h_bf) {
  __shared__ float hsb[4][8 * H];
  __shared__ float asb[4][8 * H];
  const int wave = threadIdx.x >> 6, lane = threadIdx.x & 63;
  const int n0 = (blockIdx.x * 4 + wave) * 8;
  float* ht = hsb[wave];
  float* at = asb[wave];
  for (int i = lane; i < 8 * H; i += 64) {
    int idx = n0 * H + i;
    bool ok = (idx < NN * H);
    ht[i] = ok ? h[idx] : 0.f;
    at[i] = ok ? agg[idx] : 0.f;
  }
  __syncthreads();
  const int c0 = lane, c1 = lane + 64;
  float a0[8], a1[8];
#pragma unroll
  for (int j = 0; j < 8; j++) { a0[j] = a1[j] = 0.f; }
  for (int k = 0; k < H; k += 4) {
    float w0[4], w1[4];
#pragma unroll
    for (int u = 0; u < 4; u++) { w0[u] = W1[(k + u) * H + c0]; w1[u] = W1[(k + u) * H + c1]; }
#pragma unroll
    for (int j = 0; j < 8; j++) {
      float4 v = *(const float4*)&ht[j * H + k];
      a0[j] = fmaf(v.x, w0[0], a0[j]); a0[j] = fmaf(v.y, w0[1], a0[j]);
      a0[j] = fmaf(v.z, w0[2], a0[j]); a0[j] = fmaf(v.w, w0[3], a0[j]);
      a1[j] = fmaf(v.x, w1[0], a1[j]); a1[j] = fmaf(v.y, w1[1], a1[j]);
      a1[j] = fmaf(v.z, w1[2], a1[j]); a1[j] = fmaf(v.w, w1[3], a1[j]);
    }
  }
  for (int k = 0; k < H; k += 4) {
    float w0[4], w1[4];
#pragma unroll
    for (int u = 0; u < 4; u++) { w0[u] = W1[(128 + k + u) * H + c0]; w1[u] = W1[(128 + k + u) * H + c1]; }
#pragma unroll
    for (int j = 0; j < 8; j++) {
      float4 v = *(const float4*)&at[j * H + k];
      a0[j] = fmaf(v.x, w0[0], a0[j]); a0[j] = fmaf(v.y, w0[1], a0[j]);
      a0[j] = fmaf(v.z, w0[2], a0[j]); a0[j] = fmaf(v.w, w0[3], a0[j]);
      a1[j] = fmaf(v.x, w1[0], a1[j]); a1[j] = fmaf(v.y, w1[1], a1[j]);
      a1[j] = fmaf(v.z, w1[2], a1[j]); a1[j] = fmaf(v.w, w1[3], a1[j]);
    }
  }
  const float rb10 = rb1[c0], rb11 = rb1[c1];
  float T0[8], T1[8];
#pragma unroll
  for (int j = 0; j < 8; j++) {
    T0[j] = fmaxf(a0[j] + rb10, 0.f);
    T1[j] = fmaxf(a1[j] + rb11, 0.f);
  }
  __syncthreads();
#pragma unroll
  for (int j = 0; j < 8; j++) { at[j * H + c0] = T0[j]; at[j * H + c1] = T1[j]; }
  __syncthreads();
  float m0[8], m1[8];
#pragma unroll
  for (int j = 0; j < 8; j++) { m0[j] = m1[j] = 0.f; }
  for (int k = 0; k < H; k += 4) {
    float w0[4], w1[4];
#pragma unroll
    for (int u = 0; u < 4; u++) { w0[u] = W2[(k + u) * H + c0]; w1[u] = W2[(k + u) * H + c1]; }
#pragma unroll
    for (int j = 0; j < 8; j++) {
      float4 v = *(const float4*)&at[j * H + k];
      m0[j] = fmaf(v.x, w0[0], m0[j]); m0[j] = fmaf(v.y, w0[1], m0[j]);
      m0[j] = fmaf(v.z, w0[2], m0[j]); m0[j] = fmaf(v.w, w0[3], m0[j]);
      m1[j] = fmaf(v.x, w1[0], m1[j]); m1[j] = fmaf(v.y, w1[1], m1[j]);
      m1[j] = fmaf(v.z, w1[2], m1[j]); m1[j] = fmaf(v.w, w1[3], m1[j]);
    }
  }
  const float rb20 = rb2[c0], rb21 = rb2[c1];
  const float g0 = lng[c0], g1 = lng[c1], lb0 = lnb[c0], lb1 = lnb[c1];
#pragma unroll
  for (int j = 0; j < 8; j++) {
    float v0 = ht[j * H + c0] + m0[j] + rb20;
    float v1 = ht[j * H + c1] + m1[j] + rb21;
    float mean = wsum(v0 + v1) * (1.f / H);
    float d0 = v0 - mean, d1 = v1 - mean;
    float var = wsum(d0 * d0 + d1 * d1) * (1.f / H);
    float rs = rsqrtf(var + LEPS);
    int n = n0 + j;
    if (n < NN) {
      float o0 = d0 * rs * g0 + lb0, o1 = d1 * rs * g1 + lb1;
      h[n * H + c0] = o0;
      h[n * H + c1] = o1;
      h_bf[n * H + c0] = bf16rne(o0);
      h_bf[n * H + c1] = bf16rne(o1);
    }
  }
}

// ---------------- K5: pooling ----------------
__global__ __launch_bounds__(256) void k_pool(
    const float* __restrict__ h, const int* __restrict__ batch,
    float* __restrict__ gsum, float* __restrict__ gcnt) {
  int t = blockIdx.x * blockDim.x + threadIdx.x;
  if (t >= NN * H) return;
  int n = t >> 7, c = t & 127;
  int b = batch[n];
  atomicAdd(&gsum[b * H + c], h[t]);
  if (c == 0) atomicAdd(&gcnt[b], 1.f);
}

// ---------------- K6: readout MLP ----------------
__global__ __launch_bounds__(128) void k_readout(
    const float* __restrict__ gsum, const float* __restrict__ gcnt,
    const float* __restrict__ W1, const float* __restrict__ b1,
    const float* __restrict__ W2, const float* __restrict__ b2,
    float* __restrict__ out) {
  __shared__ float gs[H];
  __shared__ float o1[H];
  int b = blockIdx.x, c = threadIdx.x;
  float cnt = fmaxf(gcnt[b], 1.f);
  gs[c] = gsum[b * H + c] / cnt;
  __syncthreads();
  float acc = b1[c];
  for (int k = 0; k < H; k++) acc = fmaf(gs[k], W1[k * H + c], acc);
  o1[c] = fmaxf(acc, 0.f);
  __syncthreads();
  if (c < 2) {
    float acc2 = b2[c];
    for (int k = 0; k < H; k++) acc2 = fmaf(o1[k], W2[k * 2 + c], acc2);
    out[b * 2 + c] = acc2;
  }
}

extern "C" void kernel_launch(void* const* d_in, const int* in_sizes, int n_in,
                              void* d_out, int out_size, void* d_ws, size_t ws_size,
                              hipStream_t stream) {
  (void)in_sizes; (void)n_in; (void)out_size; (void)ws_size;
  const float* x       = (const float*)d_in[0];
  const float* ea      = (const float*)d_in[1];
  const int*   eidx    = (const int*)d_in[2];
  const int*   batch   = (const int*)d_in[3];
  const float* n_enc_w = (const float*)d_in[4];
  const float* n_enc_b = (const float*)d_in[5];
  const float* e_enc_w = (const float*)d_in[6];
  const float* e_enc_b = (const float*)d_in[7];
  const float* n_ln_g  = (const float*)d_in[8];
  const float* n_ln_b  = (const float*)d_in[9];
  const float* e_ln_g  = (const float*)d_in[10];
  const float* e_ln_b  = (const float*)d_in[11];
  const float* msg_w1  = (const float*)d_in[12];
  const float* msg_b1  = (const float*)d_in[13];
  const float* msg_w2  = (const float*)d_in[14];
  const float* msg_b2  = (const float*)d_in[15];
  const float* gate_w  = (const float*)d_in[16];
  const float* gate_b  = (const float*)d_in[17];
  const float* res_w1  = (const float*)d_in[18];
  const float* res_b1  = (const float*)d_in[19];
  const float* res_w2  = (const float*)d_in[20];
  const float* res_b2  = (const float*)d_in[21];
  const float* ln_g    = (const float*)d_in[22];
  const float* ln_b    = (const float*)d_in[23];
  const float* ro_w1   = (const float*)d_in[24];
  const float* ro_b1   = (const float*)d_in[25];
  const float* ro_w2   = (const float*)d_in[26];
  const float* ro_b2   = (const float*)d_in[27];

  char* p = (char*)d_ws;
  float* h     = (float*)p;  p += (size_t)NN * H * 4;          // 25.6 MB
  short* h_bf  = (short*)p;  p += (size_t)NN * H * 2;          // 12.8 MB
  float* agg   = (float*)p;  p += (size_t)NN * H * 4;          // 25.6 MB
  short* ea_bf = (short*)p;  p += (size_t)NE * EIN * 2;        // 25.6 MB
  float* gsum  = (float*)p;  p += (size_t)NG * H * 4;
  float* gcnt  = (float*)p;  p += 1024;
  short* bgh   = (short*)p;  p += (size_t)3 * 65536 * 2;
  short* bm2   = (short*)p;  p += (size_t)3 * 16384 * 2;
  short* benc  = (short*)p;  p += (size_t)4096 * 2;
  unsigned* rowptr = (unsigned*)p; p += ((size_t)NN * 4 + 15) / 16 * 16;
  unsigned* cursor = (unsigned*)p; p += ((size_t)NN * 4 + 15) / 16 * 16;
  int* src_s   = (int*)p;    p += (size_t)NE * 4;
  int* dst_s   = (int*)p;    p += (size_t)NE * 4;
  // total ~97 MB

  const int node_blocks = (NN + 31) / 32;
  const int edge_blocks = NE / 64;
  const int e256 = (NE + 255) / 256;

  hipMemsetAsync(cursor, 0, (size_t)NN * 4, stream);
  k_count<<<e256, 256, 0, stream>>>(eidx, cursor);
  k_scan<<<1, 1024, 0, stream>>>(cursor, rowptr);
  hipMemsetAsync(cursor, 0, (size_t)NN * 4, stream);
  k_scatter<<<e256, 256, 0, stream>>>(eidx, ea, rowptr, cursor, src_s, dst_s, ea_bf);

  k_convert_w<<<(3 * 81920 + 4096 + 255) / 256, 256, 0, stream>>>(
      gate_w, msg_w1, msg_w2, e_enc_w, bgh, bm2, benc);
  k_node_encode<<<node_blocks, 256, 0, stream>>>(x, n_enc_w, n_enc_b, n_ln_g, n_ln_b, h, h_bf);

  for (int l = 0; l < NL; l++) {
    hipMemsetAsync(agg, 0, (size_t)NN * H * 4, stream);
    k_edge_mfma<<<edge_blocks, 256, 0, stream>>>(
        ea_bf, src_s, dst_s, h_bf, benc, e_enc_b, e_ln_g, e_ln_b,
        bgh + (size_t)l * 65536, bm2 + (size_t)l * 16384,
        gate_b + l * H, msg_b1 + l * H, msg_b2 + l * H, agg);
    k_node_update<<<node_blocks, 256, 0, stream>>>(
        agg, res_w1 + (size_t)l * 2 * H * H, res_b1 + l * H,
        res_w2 + (size_t)l * H * H, res_b2 + l * H,
        ln_g + l * H, ln_b + l * H, h, h_bf);
  }

  hipMemsetAsync(gsum, 0, ((size_t)NG * H + NG) * 4, stream);
  k_pool<<<(NN * H + 255) / 256, 256, 0, stream>>>(h, batch, gsum, gcnt);
  k_readout<<<NG, 128, 0, stream>>>(gsum, gcnt, ro_w1, ro_b1, ro_w2, ro_b2, (float*)d_out);
}